// Round 6
// baseline (262.440 us; speedup 1.0000x reference)
//
#include <hip/hip_runtime.h>
#include <hip/hip_bf16.h>

// (B,C,H,W) = (8,512,64,64)
constexpr int BATCH = 8;
constexpr int C = 512;
constexpr int HW = 4096;
constexpr long CN = (long)C * HW;   // 2,097,152
constexpr long CC = (long)C * C;    // 262,144

typedef __attribute__((ext_vector_type(8))) short short8;
typedef __attribute__((ext_vector_type(4))) short bf16x4;
typedef __attribute__((ext_vector_type(4))) float f32x4;

__device__ __forceinline__ void gload16(const void* g, void* l) {
  __builtin_amdgcn_global_load_lds(
      (const __attribute__((address_space(1))) void*)g,
      (__attribute__((address_space(3))) void*)l, 16, 0, 0);
}

__device__ __forceinline__ void hilo(float v, __hip_bfloat16& h, __hip_bfloat16& l) {
  h = __float2bfloat16(v);
  l = __float2bfloat16(v - __bfloat162float(h));
}
__device__ __forceinline__ short bfs(float v) {
  __hip_bfloat16 h = __float2bfloat16(v);
  return *(short*)&h;
}

// BK=32 LDS tile (rows x 32 k): 2 logical rows packed per 128B LDS row,
// XOR swizzle pos = ((r&1)*4 | ch) ^ ((r>>1)&7).
__device__ __forceinline__ int cidx32(int r, int ch) {   // short offset of 16B chunk
  return ((r >> 1) * 8 + ((((r & 1) << 2) | ch) ^ ((r >> 1) & 7))) * 8;
}
__device__ __forceinline__ void sdec32(int s, int& r, int& ch) {
  int R = s >> 3, q = s & 7, v = q ^ (R & 7);
  r = (R << 1) | (v >> 2);
  ch = v & 3;
}

#define WAIT_VM(n) asm volatile("s_waitcnt vmcnt(" #n ")" ::: "memory")

// ---------------------------------------------------------------------------
// convx: X fp32 [C,HW] -> Xhi bf16 [C,HW]; Xt bf16 [HW,C].
// ---------------------------------------------------------------------------
__global__ __launch_bounds__(256) void convx_k(
    const float* __restrict__ x, __hip_bfloat16* __restrict__ xhi,
    __hip_bfloat16* __restrict__ xt) {
  const int b = blockIdx.z;
  const int n0 = blockIdx.x * 64, c0 = blockIdx.y * 64;
  const float* xb = x + (long)b * CN;
  __shared__ short t[64 * 65];
  const int tid = threadIdx.x;
#pragma unroll
  for (int it = 0; it < 2; ++it) {
    int slot = it * 256 + tid;
    int r = slot >> 3, cc = (slot & 7) * 8;
    const float* src = xb + (long)(c0 + r) * HW + n0 + cc;
    f32x4 v0 = *(const f32x4*)src, v1 = *(const f32x4*)(src + 4);
    short8 hh;
#pragma unroll
    for (int e = 0; e < 4; ++e) {
      hh[e] = bfs(v0[e]);
      hh[4 + e] = bfs(v1[e]);
    }
    long idx = (long)b * CN + (long)(c0 + r) * HW + n0 + cc;
    *(short8*)((short*)xhi + idx) = hh;
#pragma unroll
    for (int e = 0; e < 8; ++e) t[r * 65 + cc + e] = hh[e];
  }
  __syncthreads();
#pragma unroll
  for (int it = 0; it < 2; ++it) {
    int slot = it * 256 + tid;
    int r = slot >> 3, cc = (slot & 7) * 8;
    short8 o;
#pragma unroll
    for (int e = 0; e < 8; ++e) o[e] = t[(cc + e) * 65 + r];
    *(short8*)((short*)xt + (long)b * CN + (long)(n0 + r) * C + c0 + cc) = o;
  }
}

// ---------------------------------------------------------------------------
// Weight prep: z=0 w_phi->hi/lo; z=1 w_theta->hi/lo; z=2 w_g->transpose bf16;
// z=3 w_mask->bf16.
// ---------------------------------------------------------------------------
__global__ __launch_bounds__(256) void wprep_k(
    const float* __restrict__ wphi, const float* __restrict__ wtheta,
    const float* __restrict__ wg, const float* __restrict__ wmask,
    __hip_bfloat16* __restrict__ wph, __hip_bfloat16* __restrict__ wpl,
    __hip_bfloat16* __restrict__ wth, __hip_bfloat16* __restrict__ wtl,
    __hip_bfloat16* __restrict__ wgT, __hip_bfloat16* __restrict__ wm16) {
  const int z = blockIdx.z;
  const int r0 = blockIdx.y * 64, c0 = blockIdx.x * 64;
  const int tid = threadIdx.x;
  if (z == 2) {
    __shared__ __hip_bfloat16 t[64][65];
#pragma unroll
    for (int i = 0; i < 16; ++i) {
      int e = i * 256 + tid;
      int r = e >> 6, c = e & 63;
      t[r][c] = __float2bfloat16(wg[(long)(r0 + r) * C + c0 + c]);
    }
    __syncthreads();
#pragma unroll
    for (int i = 0; i < 16; ++i) {
      int e = i * 256 + tid;
      int r = e >> 6, c = e & 63;
      wgT[(long)(c0 + r) * C + r0 + c] = t[c][r];
    }
  } else {
#pragma unroll
    for (int i = 0; i < 16; ++i) {
      int e = i * 256 + tid;
      int r = e >> 6, c = e & 63;
      long idx = (long)(r0 + r) * C + c0 + c;
      if (z == 0) {
        __hip_bfloat16 h, l;
        hilo(wphi[idx], h, l);
        wph[idx] = h; wpl[idx] = l;
      } else if (z == 1) {
        __hip_bfloat16 h, l;
        hilo(wtheta[idx], h, l);
        wth[idx] = h; wtl[idx] = l;
      } else {
        wm16[idx] = __float2bfloat16(wmask[idx]);
      }
    }
  }
}

// ---------------------------------------------------------------------------
// Gram partials: bf16, 128x128 triangular tiles (10/batch), K-split 4.
// BK=32, 4 LDS buffers, depth-3 counted vmcnt. XCD swizzle: b = f&7.
// ---------------------------------------------------------------------------
__global__ __launch_bounds__(256) void gram_k(
    const __hip_bfloat16* __restrict__ xhi, float* __restrict__ gpart) {
  const int f = blockIdx.x + 10 * (blockIdx.y + 4 * blockIdx.z);  // 0..319
  const int b = f & 7;
  const int rdec = f >> 3;            // 0..39
  const int ks = rdec / 10;           // 0..3
  const int tile = rdec % 10;
  int i = 0, rem0 = tile;
  while (rem0 >= 4 - i) { rem0 -= 4 - i; ++i; }
  const int j = i + rem0;
  const int m0 = i * 128, n0 = j * 128;

  const short* X = (const short*)(xhi + (long)b * CN);
  __shared__ short lds[4 * 8192];          // 64 KB: 4 x {A 128x32, B 128x32}
  const int tid = threadIdx.x, w = tid >> 6, lane = tid & 63;

  f32x4 acc[4][4] = {};
  const int wr = (w >> 1) * 64, wc = (w & 1) * 64;
  const int kbeg = ks * 1024;
  constexpr int NST = 32;

  auto STAGE = [&](int buf, int k0) {
#pragma unroll
    for (int it = 0; it < 4; ++it) {
      int s = (w & 1) * 256 + it * 64 + lane;   // 0..511 within operand
      int r, ch;
      sdec32(s, r, ch);
      int gr = (w < 2) ? (m0 + r) : (n0 + r);
      gload16(X + (long)gr * HW + k0 + ch * 8, lds + (buf * 8192 + (w >> 1) * 4096 + s * 8));
    }
  };

  const int chf = lane >> 4, rl = lane & 15;
  int aoff[4], boff[4];
#pragma unroll
  for (int mi = 0; mi < 4; ++mi) aoff[mi] = cidx32(wr + mi * 16 + rl, chf);
#pragma unroll
  for (int ni = 0; ni < 4; ++ni) boff[ni] = 4096 + cidx32(wc + ni * 16 + rl, chf);

  STAGE(0, kbeg);
  STAGE(1, kbeg + 32);
  STAGE(2, kbeg + 64);

#pragma unroll
  for (int t = 0; t < NST; ++t) {
    if (t + 3 < NST) STAGE((t + 3) & 3, kbeg + (t + 3) * 32);
    const int rm = NST - 1 - t;
    if (rm >= 3) WAIT_VM(12);
    else if (rm == 2) WAIT_VM(8);
    else if (rm == 1) WAIT_VM(4);
    else WAIT_VM(0);
    __builtin_amdgcn_s_barrier();
    const short* lb = lds + (t & 3) * 8192;
    short8 af[4], bfr[4];
#pragma unroll
    for (int mi = 0; mi < 4; ++mi) af[mi] = *(const short8*)(lb + aoff[mi]);
#pragma unroll
    for (int ni = 0; ni < 4; ++ni) bfr[ni] = *(const short8*)(lb + boff[ni]);
#pragma unroll
    for (int mi = 0; mi < 4; ++mi)
#pragma unroll
      for (int ni = 0; ni < 4; ++ni)
        acc[mi][ni] = __builtin_amdgcn_mfma_f32_16x16x32_bf16(af[mi], bfr[ni], acc[mi][ni], 0, 0, 0);
    __builtin_amdgcn_s_barrier();
  }

  float* P = gpart + ((((long)b * 10 + tile) * 4 + ks) << 14);
#pragma unroll
  for (int mi = 0; mi < 4; ++mi)
#pragma unroll
    for (int ni = 0; ni < 4; ++ni)
#pragma unroll
      for (int rr = 0; rr < 4; ++rr) {
        int row = wr + mi * 16 + (lane >> 4) * 4 + rr;
        int col = wc + ni * 16 + (lane & 15);
        P[row * 128 + col] = acc[mi][ni][rr];
      }
}

// ---------------------------------------------------------------------------
// Gram reduce: sum 4 K-partials over a 64x128 half-tile, hi/lo split, write
// direct + LDS-transposed mirror. Flat grid (160), b = id&7.
// ---------------------------------------------------------------------------
__global__ __launch_bounds__(256) void gred_k(
    const float* __restrict__ gpart, __hip_bfloat16* __restrict__ gh,
    __hip_bfloat16* __restrict__ gl) {
  const int id = blockIdx.x;
  const int b = id & 7;
  const int t2 = id >> 3;
  const int tile = t2 % 10;
  const int half = t2 / 10;
  int i = 0, rem = tile;
  while (rem >= 4 - i) { rem -= 4 - i; ++i; }
  const int j = i + rem;
  const int m0 = i * 128, n0 = j * 128;
  const float* P = gpart + (((long)b * 10 + tile) << 16) + half * 8192;
  __shared__ float T[128][65];
  const int tid = threadIdx.x;
  const long dbase = (long)b * CC;

#pragma unroll
  for (int q = 0; q < 8; ++q) {
    int e = q * 1024 + tid * 4;
    int r = e >> 7, c = e & 127;
    f32x4 s = {};
#pragma unroll
    for (int ks = 0; ks < 4; ++ks) s += *(const f32x4*)(P + (ks << 14) + e);
    bf16x4 hh, ll;
#pragma unroll
    for (int u = 0; u < 4; ++u) {
      __hip_bfloat16 h, l;
      hilo(s[u], h, l);
      hh[u] = *(short*)&h;
      ll[u] = *(short*)&l;
      T[c + u][r] = s[u];
    }
    long idx = dbase + (long)(m0 + half * 64 + r) * 512 + n0 + c;
    *(bf16x4*)((short*)gh + idx) = hh;
    *(bf16x4*)((short*)gl + idx) = ll;
  }
  if (i != j) {
    __syncthreads();
#pragma unroll
    for (int q = 0; q < 8; ++q) {
      int e = q * 1024 + tid * 4;
      int rp = e >> 6, cp = e & 63;
      bf16x4 hh, ll;
#pragma unroll
      for (int u = 0; u < 4; ++u) {
        __hip_bfloat16 h, l;
        hilo(T[rp][cp + u], h, l);
        hh[u] = *(short*)&h;
        ll[u] = *(short*)&l;
      }
      long idx = dbase + (long)(n0 + rp) * 512 + m0 + half * 64 + cp;
      *(bf16x4*)((short*)gh + idx) = hh;
      *(bf16x4*)((short*)gl + idx) = ll;
    }
  }
}

// ---------------------------------------------------------------------------
// Small NT MFMA GEMM: C[512,512] = A[512,K=512] * B[512,K]^T, per batch.
// AH/BH hi/lo split (3 MFMA passes). EPI 0: hi/lo out; 1: fp32; 2: bf16.
// BK=32, 4 LDS buffers, depth-3 counted vmcnt (T3+T4, big_k template).
// PAN4: panels {Ah,Al,Bh,Bl} x 2048 shorts/buffer (64 KB total).
// PAN2: panels {A,B} (32 KB total). Flat grid (512), b = id&7.
// ---------------------------------------------------------------------------
template <int AH, int BH, int EPI>
__global__ __launch_bounds__(256) void nt_small(
    const __hip_bfloat16* __restrict__ Ah_, const __hip_bfloat16* __restrict__ Al_,
    const __hip_bfloat16* __restrict__ Bh_, const __hip_bfloat16* __restrict__ Bl_,
    long aStr, long bStr, void* __restrict__ out1, void* __restrict__ out2) {
  const int id = blockIdx.x;
  const int b = id & 7;
  const int rest = id >> 3;
  const int m0 = (rest >> 3) * 64, n0 = (rest & 7) * 64;
  const short* Ahp = (const short*)(Ah_ + (long)b * aStr);
  const short* Alp = AH ? (const short*)(Al_ + (long)b * aStr) : nullptr;
  const short* Bhp = (const short*)(Bh_ + (long)b * bStr);
  const short* Blp = BH ? (const short*)(Bl_ + (long)b * bStr) : nullptr;
  constexpr int PAN = (AH && BH) ? 4 : 2;        // panels per buffer
  constexpr int BUFS = PAN * 2048;               // shorts per buffer
  __shared__ short lds[4 * BUFS];
  const int tid = threadIdx.x, w = tid >> 6, lane = tid & 63;

  f32x4 acc[2][2] = {};
  const int wr = (w >> 1) * 32, wc = (w & 1) * 32;
  constexpr int NST = 16;

  auto STAGE = [&](int buf, int k0) {
    if constexpr (AH && BH) {
      // wave w stages panel w (Ah,Al,Bh,Bl); 256 chunks, 4 loads/wave
      const short* src = (w == 0) ? Ahp : (w == 1) ? Alp : (w == 2) ? Bhp : Blp;
      const int rowbase = (w & 2) ? n0 : m0;
#pragma unroll
      for (int it = 0; it < 4; ++it) {
        int s = it * 64 + lane;                  // 0..255
        int r, ch;
        sdec32(s, r, ch);
        gload16(src + (long)(rowbase + r) * 512 + k0 + ch * 8,
                lds + ((buf * PAN + w) * 2048 + s * 8));
      }
    } else {
      // waves 0,1 stage A; 2,3 stage B; 2 loads/wave
      const short* src = (w < 2) ? Ahp : Bhp;
      const int rowbase = (w < 2) ? m0 : n0;
#pragma unroll
      for (int it = 0; it < 2; ++it) {
        int s = (w & 1) * 128 + it * 64 + lane;  // 0..255 across wave pair
        int r, ch;
        sdec32(s, r, ch);
        gload16(src + (long)(rowbase + r) * 512 + k0 + ch * 8,
                lds + ((buf * PAN + (w >> 1)) * 2048 + s * 8));
      }
    }
  };

  const int chf = lane >> 4, rl = lane & 15;
  int aoff[2], boff[2];
#pragma unroll
  for (int mi = 0; mi < 2; ++mi) aoff[mi] = cidx32(wr + mi * 16 + rl, chf);
#pragma unroll
  for (int ni = 0; ni < 2; ++ni) boff[ni] = cidx32(wc + ni * 16 + rl, chf);

  STAGE(0, 0);
  STAGE(1, 32);
  STAGE(2, 64);

#pragma unroll
  for (int t = 0; t < NST; ++t) {
    if (t + 3 < NST) STAGE((t + 3) & 3, (t + 3) * 32);
    const int rm = NST - 1 - t;
    if constexpr (PAN == 4) {
      if (rm >= 3) WAIT_VM(12);
      else if (rm == 2) WAIT_VM(8);
      else if (rm == 1) WAIT_VM(4);
      else WAIT_VM(0);
    } else {
      if (rm >= 3) WAIT_VM(6);
      else if (rm == 2) WAIT_VM(4);
      else if (rm == 1) WAIT_VM(2);
      else WAIT_VM(0);
    }
    __builtin_amdgcn_s_barrier();
    const short* lb = lds + (t & 3) * BUFS;
    short8 ah[2], al[2], bh[2], bl[2];
#pragma unroll
    for (int mi = 0; mi < 2; ++mi) {
      ah[mi] = *(const short8*)(lb + aoff[mi]);
      if constexpr (AH) al[mi] = *(const short8*)(lb + 2048 + aoff[mi]);
    }
#pragma unroll
    for (int ni = 0; ni < 2; ++ni) {
      bh[ni] = *(const short8*)(lb + ((AH && BH) ? 4096 : 2048) + boff[ni]);
      if constexpr (BH) bl[ni] = *(const short8*)(lb + 6144 + boff[ni]);
    }
#pragma unroll
    for (int mi = 0; mi < 2; ++mi)
#pragma unroll
      for (int ni = 0; ni < 2; ++ni) {
        acc[mi][ni] = __builtin_amdgcn_mfma_f32_16x16x32_bf16(ah[mi], bh[ni], acc[mi][ni], 0, 0, 0);
        if constexpr (BH)
          acc[mi][ni] = __builtin_amdgcn_mfma_f32_16x16x32_bf16(ah[mi], bl[ni], acc[mi][ni], 0, 0, 0);
        if constexpr (AH)
          acc[mi][ni] = __builtin_amdgcn_mfma_f32_16x16x32_bf16(al[mi], bh[ni], acc[mi][ni], 0, 0, 0);
      }
    __builtin_amdgcn_s_barrier();
  }

#pragma unroll
  for (int mi = 0; mi < 2; ++mi)
#pragma unroll
    for (int ni = 0; ni < 2; ++ni)
#pragma unroll
      for (int rr = 0; rr < 4; ++rr) {
        int row = m0 + wr + mi * 16 + (lane >> 4) * 4 + rr;
        int col = n0 + wc + ni * 16 + (lane & 15);
        long idx = (long)b * CC + (long)row * 512 + col;
        float v = acc[mi][ni][rr];
        if constexpr (EPI == 0) {
          __hip_bfloat16 h, l;
          hilo(v, h, l);
          ((__hip_bfloat16*)out1)[idx] = h;
          ((__hip_bfloat16*)out2)[idx] = l;
        } else if constexpr (EPI == 1) {
          ((float*)out1)[idx] = v;
        } else {
          ((__hip_bfloat16*)out1)[idx] = __float2bfloat16(v);
        }
      }
}

// ---------------------------------------------------------------------------
// Row softmax over 512 cols, fp32 in -> bf16 out. One row per WAVE,
// shuffle reductions, no LDS/barriers. Flat grid (1024), b = id&7.
// ---------------------------------------------------------------------------
__global__ __launch_bounds__(256) void softmax_k(const float* __restrict__ a,
                                                 __hip_bfloat16* __restrict__ o) {
  const int id = blockIdx.x;
  const int b = id & 7, rg = id >> 3;           // rg in [0,128)
  const int w = threadIdx.x >> 6, lane = threadIdx.x & 63;
  const long row = (long)b * 512 + rg * 4 + w;
  const float* rp = a + row * 512 + lane * 8;
  f32x4 v0 = *(const f32x4*)rp, v1 = *(const f32x4*)(rp + 4);
  float mx = fmaxf(fmaxf(fmaxf(v0[0], v0[1]), fmaxf(v0[2], v0[3])),
                   fmaxf(fmaxf(v1[0], v1[1]), fmaxf(v1[2], v1[3])));
#pragma unroll
  for (int s = 1; s < 64; s <<= 1) mx = fmaxf(mx, __shfl_xor(mx, s));
  float e[8];
#pragma unroll
  for (int k = 0; k < 4; ++k) {
    e[k] = expf(v0[k] - mx);
    e[4 + k] = expf(v1[k] - mx);
  }
  float sum = ((e[0] + e[1]) + (e[2] + e[3])) + ((e[4] + e[5]) + (e[6] + e[7]));
#pragma unroll
  for (int s = 1; s < 64; s <<= 1) sum += __shfl_xor(sum, s);
  const float inv = 1.0f / sum;
  short8 o8;
#pragma unroll
  for (int k = 0; k < 8; ++k) o8[k] = bfs(e[k] * inv);
  *(short8*)((short*)o + row * 512 + lane * 8) = o8;
}

// ---------------------------------------------------------------------------
// Big NT MFMA GEMM, 128x128 tile, M=512 N=4096 K=512. Flat grid (128,1,8),
// XCD-aware bijective swizzle. BK=32, 4 LDS buffers, depth-3 counted vmcnt.
// MODE 0: y = Mb (NT) Xt, permuted B-rows -> yvT bf16 (== permute+view).
// MODE 1: out = gamma*(w_mask (NT) yvT) + x, fp32 store. x is PREFETCHED
//   into registers during the K-loop (4 loads/stage interleaved with the
//   staging pipeline; vmcnt schedule accounts for them: wait N = #loads
//   issued after the consumed stage = 16/20/24 ramp, 28 steady, 24/20/16
//   tail, 0 before the epilogue). Epilogue is pure fma+store.
// ---------------------------------------------------------------------------
template <int MODE>
__global__ __launch_bounds__(256) void big_k(
    const __hip_bfloat16* __restrict__ Aw, const __hip_bfloat16* __restrict__ Bm,
    void* __restrict__ Cout, const float* __restrict__ x,
    const float* __restrict__ gammaPtr, long aStride) {
  const int b = blockIdx.z;
  const int lin = ((blockIdx.x & 7) << 4) | (blockIdx.x >> 3);  // XCD swizzle
  const int m0 = (lin & 3) * 128;
  const int n0 = (lin >> 2) * 128;
  const short* A = (const short*)(Aw + (long)b * aStride);
  const short* B = (const short*)(Bm + (long)b * CN);
  __shared__ short lds[4 * 8192];          // 64 KB: 4 x {A 128x32, B 128x32}
  const int tid = threadIdx.x, w = tid >> 6, lane = tid & 63;

  f32x4 acc[4][4] = {};
  const int wr = (w >> 1) * 64, wc = (w & 1) * 64;
  constexpr int NST = 16;

  const float* xb = (MODE == 1) ? x + (long)b * CN : nullptr;
  float xv[16][4];

  auto STAGE = [&](int buf, int k0) {
    short* lb = lds + buf * 8192;
#pragma unroll
    for (int it = 0; it < 4; ++it) {
      int s = (w & 1) * 256 + it * 64 + lane;   // 0..511 within operand
      int r, ch;
      sdec32(s, r, ch);
      if (w < 2) {
        gload16(A + (long)(m0 + r) * 512 + k0 + ch * 8, lb + s * 8);
      } else {
        int gr = (MODE == 0) ? (n0 + (r & 15) * 8 + (r >> 4)) : (n0 + r);
        gload16(B + (long)gr * 512 + k0 + ch * 8, lb + 4096 + s * 8);
      }
    }
  };

  const int chf = lane >> 4, rl = lane & 15;
  int aoff[4], boff[4];
#pragma unroll
  for (int mi = 0; mi < 4; ++mi) aoff[mi] = cidx32(wr + mi * 16 + rl, chf);
#pragma unroll
  for (int ni = 0; ni < 4; ++ni) boff[ni] = 4096 + cidx32(wc + ni * 16 + rl, chf);

  STAGE(0, 0);
  STAGE(1, 32);
  STAGE(2, 64);

#pragma unroll
  for (int t = 0; t < NST; ++t) {
    if (t + 3 < NST) STAGE((t + 3) & 3, (t + 3) * 32);
    if constexpr (MODE == 1) {
      // x prefetch batch t: (mi,ni) = (t>>2, t&3), 4 rows
      const int mi = t >> 2, ni = t & 3;
      const long base = (long)(m0 + wr + mi * 16 + chf * 4) * HW +
                        n0 + wc + ni * 16 + rl;
#pragma unroll
      for (int r = 0; r < 4; ++r) xv[t][r] = xb[base + (long)r * HW];
    }
    const int rm = NST - 1 - t;
    if constexpr (MODE == 1) {
      // wait N = loads issued after stage t's 4 staging loads
      if (t == 0) WAIT_VM(16);
      else if (t == 1) WAIT_VM(20);
      else if (t == 2) WAIT_VM(24);
      else if (t <= 12) WAIT_VM(28);
      else if (t == 13) WAIT_VM(24);
      else if (t == 14) WAIT_VM(20);
      else WAIT_VM(16);
    } else {
      if (rm >= 3) WAIT_VM(12);
      else if (rm == 2) WAIT_VM(8);
      else if (rm == 1) WAIT_VM(4);
      else WAIT_VM(0);
    }
    __builtin_amdgcn_s_barrier();
    const short* lb = lds + (t & 3) * 8192;
    short8 af[4], bfr[4];
#pragma unroll
    for (int mi = 0; mi < 4; ++mi) af[mi] = *(const short8*)(lb + aoff[mi]);
#pragma unroll
    for (int ni = 0; ni < 4; ++ni) bfr[ni] = *(const short8*)(lb + boff[ni]);
#pragma unroll
    for (int mi = 0; mi < 4; ++mi)
#pragma unroll
      for (int ni = 0; ni < 4; ++ni)
        acc[mi][ni] = __builtin_amdgcn_mfma_f32_16x16x32_bf16(af[mi], bfr[ni], acc[mi][ni], 0, 0, 0);
    __builtin_amdgcn_s_barrier();
  }

  if (MODE == 0) {
    __hip_bfloat16* yv = (__hip_bfloat16*)Cout + (long)b * CN;
    const int u = lane & 15;
#pragma unroll
    for (int mi = 0; mi < 4; ++mi)
#pragma unroll
      for (int ni = 0; ni < 4; ++ni) {
        int t = (wc >> 4) + ni;
        long base = ((long)(t * 512 + m0 + wr + mi * 16 + (lane >> 4) * 4)) * 512 +
                    (n0 >> 3) + u;
#pragma unroll
        for (int r = 0; r < 4; ++r)
          yv[base + (long)r * 512] = __float2bfloat16(acc[mi][ni][r]);
      }
  } else {
    WAIT_VM(0);   // all x prefetches complete
    float* outp = (float*)Cout + (long)b * CN;
    const float g0 = gammaPtr[0];
#pragma unroll
    for (int mi = 0; mi < 4; ++mi)
#pragma unroll
      for (int ni = 0; ni < 4; ++ni)
#pragma unroll
        for (int r = 0; r < 4; ++r) {
          long idx = (long)(m0 + wr + mi * 16 + chf * 4 + r) * HW +
                     n0 + wc + ni * 16 + rl;
          outp[idx] = g0 * acc[mi][ni][r] + xv[mi * 4 + ni][r];
        }
  }
}

// ---------------------------------------------------------------------------
// Orchestration. Workspace ~107 MB.
// ---------------------------------------------------------------------------
extern "C" void kernel_launch(void* const* d_in, const int* in_sizes, int n_in,
                              void* d_out, int out_size, void* d_ws, size_t ws_size,
                              hipStream_t stream) {
  const float* x       = (const float*)d_in[0];
  const float* w_phi   = (const float*)d_in[1];
  const float* w_theta = (const float*)d_in[2];
  const float* w_g     = (const float*)d_in[3];
  const float* w_mask  = (const float*)d_in[4];
  const float* gamma   = (const float*)d_in[5];
  float* out = (float*)d_out;

  __hip_bfloat16* xhi = (__hip_bfloat16*)d_ws;
  __hip_bfloat16* xt  = xhi + BATCH * CN;
  __hip_bfloat16* gh  = xt + BATCH * CN;
  __hip_bfloat16* gl  = gh + BATCH * CC;
  __hip_bfloat16* t1h = gl + BATCH * CC;
  __hip_bfloat16* t1l = t1h + BATCH * CC;
  __hip_bfloat16* wph = t1l + BATCH * CC;
  __hip_bfloat16* wpl = wph + CC;
  __hip_bfloat16* wth = wpl + CC;
  __hip_bfloat16* wtl = wth + CC;
  __hip_bfloat16* wgT = wtl + CC;
  __hip_bfloat16* wm16 = wgT + CC;
  float* gpart = (float*)(wm16 + CC);     // 21 MB
  // aliases (stream-ordered lifetimes don't overlap):
  float* logits           = (float*)gh;
  __hip_bfloat16* attn16  = t1h;
  __hip_bfloat16* mb16    = t1l;
  __hip_bfloat16* yvT     = xhi;

  convx_k<<<dim3(64, 8, BATCH), 256, 0, stream>>>(x, xhi, xt);
  wprep_k<<<dim3(8, 8, 4), 256, 0, stream>>>(w_phi, w_theta, w_g, w_mask,
                                             wph, wpl, wth, wtl, wgT, wm16);
  gram_k<<<dim3(10, 4, BATCH), 256, 0, stream>>>(xhi, gpart);
  gred_k<<<dim3(160, 1, 1), 256, 0, stream>>>(gpart, gh, gl);
  nt_small<1, 1, 0><<<dim3(512, 1, 1), 256, 0, stream>>>(
      wph, wpl, gh, gl, 0, CC, t1h, t1l);
  nt_small<1, 1, 1><<<dim3(512, 1, 1), 256, 0, stream>>>(
      t1h, t1l, wth, wtl, CC, 0, logits, nullptr);
  softmax_k<<<dim3(1024, 1, 1), dim3(256), 0, stream>>>(logits, attn16);
  nt_small<0, 0, 2><<<dim3(512, 1, 1), 256, 0, stream>>>(
      attn16, nullptr, wgT, nullptr, CC, 0, mb16, nullptr);
  big_k<0><<<dim3(128, 1, BATCH), 256, 0, stream>>>(mb16, xt, yvT, nullptr, nullptr, CC);
  big_k<1><<<dim3(128, 1, BATCH), 256, 0, stream>>>(wm16, yvT, out, x, gamma, 0);
}

// Round 7
// 261.416 us; speedup vs baseline: 1.0039x; 1.0039x over previous
//
#include <hip/hip_runtime.h>
#include <hip/hip_bf16.h>

// (B,C,H,W) = (8,512,64,64)
constexpr int BATCH = 8;
constexpr int C = 512;
constexpr int HW = 4096;
constexpr long CN = (long)C * HW;   // 2,097,152
constexpr long CC = (long)C * C;    // 262,144

typedef __attribute__((ext_vector_type(8))) short short8;
typedef __attribute__((ext_vector_type(4))) short bf16x4;
typedef __attribute__((ext_vector_type(4))) float f32x4;

__device__ __forceinline__ void gload16(const void* g, void* l) {
  __builtin_amdgcn_global_load_lds(
      (const __attribute__((address_space(1))) void*)g,
      (__attribute__((address_space(3))) void*)l, 16, 0, 0);
}

__device__ __forceinline__ void hilo(float v, __hip_bfloat16& h, __hip_bfloat16& l) {
  h = __float2bfloat16(v);
  l = __float2bfloat16(v - __bfloat162float(h));
}
__device__ __forceinline__ short bfs(float v) {
  __hip_bfloat16 h = __float2bfloat16(v);
  return *(short*)&h;
}

// BK=32 LDS tile (rows x 32 k): 2 logical rows packed per 128B LDS row,
// XOR swizzle pos = ((r&1)*4 | ch) ^ ((r>>1)&7).
__device__ __forceinline__ int cidx32(int r, int ch) {   // short offset of 16B chunk
  return ((r >> 1) * 8 + ((((r & 1) << 2) | ch) ^ ((r >> 1) & 7))) * 8;
}
__device__ __forceinline__ void sdec32(int s, int& r, int& ch) {
  int R = s >> 3, q = s & 7, v = q ^ (R & 7);
  r = (R << 1) | (v >> 2);
  ch = v & 3;
}

#define WAIT_VM(n) asm volatile("s_waitcnt vmcnt(" #n ")" ::: "memory")

// ---------------------------------------------------------------------------
// convx: X fp32 [C,HW] -> Xhi bf16 [C,HW]; Xt bf16 [HW,C].
// ---------------------------------------------------------------------------
__global__ __launch_bounds__(256) void convx_k(
    const float* __restrict__ x, __hip_bfloat16* __restrict__ xhi,
    __hip_bfloat16* __restrict__ xt) {
  const int b = blockIdx.z;
  const int n0 = blockIdx.x * 64, c0 = blockIdx.y * 64;
  const float* xb = x + (long)b * CN;
  __shared__ short t[64 * 65];
  const int tid = threadIdx.x;
#pragma unroll
  for (int it = 0; it < 2; ++it) {
    int slot = it * 256 + tid;
    int r = slot >> 3, cc = (slot & 7) * 8;
    const float* src = xb + (long)(c0 + r) * HW + n0 + cc;
    f32x4 v0 = *(const f32x4*)src, v1 = *(const f32x4*)(src + 4);
    short8 hh;
#pragma unroll
    for (int e = 0; e < 4; ++e) {
      hh[e] = bfs(v0[e]);
      hh[4 + e] = bfs(v1[e]);
    }
    long idx = (long)b * CN + (long)(c0 + r) * HW + n0 + cc;
    *(short8*)((short*)xhi + idx) = hh;
#pragma unroll
    for (int e = 0; e < 8; ++e) t[r * 65 + cc + e] = hh[e];
  }
  __syncthreads();
#pragma unroll
  for (int it = 0; it < 2; ++it) {
    int slot = it * 256 + tid;
    int r = slot >> 3, cc = (slot & 7) * 8;
    short8 o;
#pragma unroll
    for (int e = 0; e < 8; ++e) o[e] = t[(cc + e) * 65 + r];
    *(short8*)((short*)xt + (long)b * CN + (long)(n0 + r) * C + c0 + cc) = o;
  }
}

// ---------------------------------------------------------------------------
// Weight prep: z=0 w_phi->hi/lo; z=1 w_theta->hi/lo; z=2 w_g->transpose bf16;
// z=3 w_mask->bf16.
// ---------------------------------------------------------------------------
__global__ __launch_bounds__(256) void wprep_k(
    const float* __restrict__ wphi, const float* __restrict__ wtheta,
    const float* __restrict__ wg, const float* __restrict__ wmask,
    __hip_bfloat16* __restrict__ wph, __hip_bfloat16* __restrict__ wpl,
    __hip_bfloat16* __restrict__ wth, __hip_bfloat16* __restrict__ wtl,
    __hip_bfloat16* __restrict__ wgT, __hip_bfloat16* __restrict__ wm16) {
  const int z = blockIdx.z;
  const int r0 = blockIdx.y * 64, c0 = blockIdx.x * 64;
  const int tid = threadIdx.x;
  if (z == 2) {
    __shared__ __hip_bfloat16 t[64][65];
#pragma unroll
    for (int i = 0; i < 16; ++i) {
      int e = i * 256 + tid;
      int r = e >> 6, c = e & 63;
      t[r][c] = __float2bfloat16(wg[(long)(r0 + r) * C + c0 + c]);
    }
    __syncthreads();
#pragma unroll
    for (int i = 0; i < 16; ++i) {
      int e = i * 256 + tid;
      int r = e >> 6, c = e & 63;
      wgT[(long)(c0 + r) * C + r0 + c] = t[c][r];
    }
  } else {
#pragma unroll
    for (int i = 0; i < 16; ++i) {
      int e = i * 256 + tid;
      int r = e >> 6, c = e & 63;
      long idx = (long)(r0 + r) * C + c0 + c;
      if (z == 0) {
        __hip_bfloat16 h, l;
        hilo(wphi[idx], h, l);
        wph[idx] = h; wpl[idx] = l;
      } else if (z == 1) {
        __hip_bfloat16 h, l;
        hilo(wtheta[idx], h, l);
        wth[idx] = h; wtl[idx] = l;
      } else {
        wm16[idx] = __float2bfloat16(wmask[idx]);
      }
    }
  }
}

// ---------------------------------------------------------------------------
// Gram partials: bf16, 128x128 triangular tiles (10/batch), K-split 4.
// BK=32, 4 LDS buffers, depth-3 counted vmcnt. XCD swizzle: b = f&7.
// ---------------------------------------------------------------------------
__global__ __launch_bounds__(256) void gram_k(
    const __hip_bfloat16* __restrict__ xhi, float* __restrict__ gpart) {
  const int f = blockIdx.x + 10 * (blockIdx.y + 4 * blockIdx.z);  // 0..319
  const int b = f & 7;
  const int rdec = f >> 3;            // 0..39
  const int ks = rdec / 10;           // 0..3
  const int tile = rdec % 10;
  int i = 0, rem0 = tile;
  while (rem0 >= 4 - i) { rem0 -= 4 - i; ++i; }
  const int j = i + rem0;
  const int m0 = i * 128, n0 = j * 128;

  const short* X = (const short*)(xhi + (long)b * CN);
  __shared__ short lds[4 * 8192];          // 64 KB: 4 x {A 128x32, B 128x32}
  const int tid = threadIdx.x, w = tid >> 6, lane = tid & 63;

  f32x4 acc[4][4] = {};
  const int wr = (w >> 1) * 64, wc = (w & 1) * 64;
  const int kbeg = ks * 1024;
  constexpr int NST = 32;

  auto STAGE = [&](int buf, int k0) {
#pragma unroll
    for (int it = 0; it < 4; ++it) {
      int s = (w & 1) * 256 + it * 64 + lane;   // 0..511 within operand
      int r, ch;
      sdec32(s, r, ch);
      int gr = (w < 2) ? (m0 + r) : (n0 + r);
      gload16(X + (long)gr * HW + k0 + ch * 8, lds + (buf * 8192 + (w >> 1) * 4096 + s * 8));
    }
  };

  const int chf = lane >> 4, rl = lane & 15;
  int aoff[4], boff[4];
#pragma unroll
  for (int mi = 0; mi < 4; ++mi) aoff[mi] = cidx32(wr + mi * 16 + rl, chf);
#pragma unroll
  for (int ni = 0; ni < 4; ++ni) boff[ni] = 4096 + cidx32(wc + ni * 16 + rl, chf);

  STAGE(0, kbeg);
  STAGE(1, kbeg + 32);
  STAGE(2, kbeg + 64);

#pragma unroll
  for (int t = 0; t < NST; ++t) {
    if (t + 3 < NST) STAGE((t + 3) & 3, kbeg + (t + 3) * 32);
    const int rm = NST - 1 - t;
    if (rm >= 3) WAIT_VM(12);
    else if (rm == 2) WAIT_VM(8);
    else if (rm == 1) WAIT_VM(4);
    else WAIT_VM(0);
    __builtin_amdgcn_s_barrier();
    const short* lb = lds + (t & 3) * 8192;
    short8 af[4], bfr[4];
#pragma unroll
    for (int mi = 0; mi < 4; ++mi) af[mi] = *(const short8*)(lb + aoff[mi]);
#pragma unroll
    for (int ni = 0; ni < 4; ++ni) bfr[ni] = *(const short8*)(lb + boff[ni]);
#pragma unroll
    for (int mi = 0; mi < 4; ++mi)
#pragma unroll
      for (int ni = 0; ni < 4; ++ni)
        acc[mi][ni] = __builtin_amdgcn_mfma_f32_16x16x32_bf16(af[mi], bfr[ni], acc[mi][ni], 0, 0, 0);
    __builtin_amdgcn_s_barrier();
  }

  float* P = gpart + ((((long)b * 10 + tile) * 4 + ks) << 14);
#pragma unroll
  for (int mi = 0; mi < 4; ++mi)
#pragma unroll
    for (int ni = 0; ni < 4; ++ni)
#pragma unroll
      for (int rr = 0; rr < 4; ++rr) {
        int row = wr + mi * 16 + (lane >> 4) * 4 + rr;
        int col = wc + ni * 16 + (lane & 15);
        P[row * 128 + col] = acc[mi][ni][rr];
      }
}

// ---------------------------------------------------------------------------
// Gram reduce: sum 4 K-partials over a 64x128 half-tile, hi/lo split, write
// direct + LDS-transposed mirror. Flat grid (160), b = id&7.
// ---------------------------------------------------------------------------
__global__ __launch_bounds__(256) void gred_k(
    const float* __restrict__ gpart, __hip_bfloat16* __restrict__ gh,
    __hip_bfloat16* __restrict__ gl) {
  const int id = blockIdx.x;
  const int b = id & 7;
  const int t2 = id >> 3;
  const int tile = t2 % 10;
  const int half = t2 / 10;
  int i = 0, rem = tile;
  while (rem >= 4 - i) { rem -= 4 - i; ++i; }
  const int j = i + rem;
  const int m0 = i * 128, n0 = j * 128;
  const float* P = gpart + (((long)b * 10 + tile) << 16) + half * 8192;
  __shared__ float T[128][65];
  const int tid = threadIdx.x;
  const long dbase = (long)b * CC;

#pragma unroll
  for (int q = 0; q < 8; ++q) {
    int e = q * 1024 + tid * 4;
    int r = e >> 7, c = e & 127;
    f32x4 s = {};
#pragma unroll
    for (int ks = 0; ks < 4; ++ks) s += *(const f32x4*)(P + (ks << 14) + e);
    bf16x4 hh, ll;
#pragma unroll
    for (int u = 0; u < 4; ++u) {
      __hip_bfloat16 h, l;
      hilo(s[u], h, l);
      hh[u] = *(short*)&h;
      ll[u] = *(short*)&l;
      T[c + u][r] = s[u];
    }
    long idx = dbase + (long)(m0 + half * 64 + r) * 512 + n0 + c;
    *(bf16x4*)((short*)gh + idx) = hh;
    *(bf16x4*)((short*)gl + idx) = ll;
  }
  if (i != j) {
    __syncthreads();
#pragma unroll
    for (int q = 0; q < 8; ++q) {
      int e = q * 1024 + tid * 4;
      int rp = e >> 6, cp = e & 63;
      bf16x4 hh, ll;
#pragma unroll
      for (int u = 0; u < 4; ++u) {
        __hip_bfloat16 h, l;
        hilo(T[rp][cp + u], h, l);
        hh[u] = *(short*)&h;
        ll[u] = *(short*)&l;
      }
      long idx = dbase + (long)(n0 + rp) * 512 + m0 + half * 64 + cp;
      *(bf16x4*)((short*)gh + idx) = hh;
      *(bf16x4*)((short*)gl + idx) = ll;
    }
  }
}

// ---------------------------------------------------------------------------
// Small NT MFMA GEMM: C[512,512] = A[512,K=512] * B[512,K]^T, per batch.
// AH/BH hi/lo split (3 MFMA passes). EPI 0: hi/lo out; 1: fp32; 2: bf16.
// BK=32, 4 LDS buffers, depth-3 counted vmcnt (T3+T4, big_k template).
// PAN4: panels {Ah,Al,Bh,Bl} x 2048 shorts/buffer (64 KB total).
// PAN2: panels {A,B} (32 KB total). Flat grid (512), b = id&7.
// ---------------------------------------------------------------------------
template <int AH, int BH, int EPI>
__global__ __launch_bounds__(256) void nt_small(
    const __hip_bfloat16* __restrict__ Ah_, const __hip_bfloat16* __restrict__ Al_,
    const __hip_bfloat16* __restrict__ Bh_, const __hip_bfloat16* __restrict__ Bl_,
    long aStr, long bStr, void* __restrict__ out1, void* __restrict__ out2) {
  const int id = blockIdx.x;
  const int b = id & 7;
  const int rest = id >> 3;
  const int m0 = (rest >> 3) * 64, n0 = (rest & 7) * 64;
  const short* Ahp = (const short*)(Ah_ + (long)b * aStr);
  const short* Alp = AH ? (const short*)(Al_ + (long)b * aStr) : nullptr;
  const short* Bhp = (const short*)(Bh_ + (long)b * bStr);
  const short* Blp = BH ? (const short*)(Bl_ + (long)b * bStr) : nullptr;
  constexpr int PAN = (AH && BH) ? 4 : 2;        // panels per buffer
  constexpr int BUFS = PAN * 2048;               // shorts per buffer
  __shared__ short lds[4 * BUFS];
  const int tid = threadIdx.x, w = tid >> 6, lane = tid & 63;

  f32x4 acc[2][2] = {};
  const int wr = (w >> 1) * 32, wc = (w & 1) * 32;
  constexpr int NST = 16;

  auto STAGE = [&](int buf, int k0) {
    if constexpr (AH && BH) {
      // wave w stages panel w (Ah,Al,Bh,Bl); 256 chunks, 4 loads/wave
      const short* src = (w == 0) ? Ahp : (w == 1) ? Alp : (w == 2) ? Bhp : Blp;
      const int rowbase = (w & 2) ? n0 : m0;
#pragma unroll
      for (int it = 0; it < 4; ++it) {
        int s = it * 64 + lane;                  // 0..255
        int r, ch;
        sdec32(s, r, ch);
        gload16(src + (long)(rowbase + r) * 512 + k0 + ch * 8,
                lds + ((buf * PAN + w) * 2048 + s * 8));
      }
    } else {
      // waves 0,1 stage A; 2,3 stage B; 2 loads/wave
      const short* src = (w < 2) ? Ahp : Bhp;
      const int rowbase = (w < 2) ? m0 : n0;
#pragma unroll
      for (int it = 0; it < 2; ++it) {
        int s = (w & 1) * 128 + it * 64 + lane;  // 0..255 across wave pair
        int r, ch;
        sdec32(s, r, ch);
        gload16(src + (long)(rowbase + r) * 512 + k0 + ch * 8,
                lds + ((buf * PAN + (w >> 1)) * 2048 + s * 8));
      }
    }
  };

  const int chf = lane >> 4, rl = lane & 15;
  int aoff[2], boff[2];
#pragma unroll
  for (int mi = 0; mi < 2; ++mi) aoff[mi] = cidx32(wr + mi * 16 + rl, chf);
#pragma unroll
  for (int ni = 0; ni < 2; ++ni) boff[ni] = cidx32(wc + ni * 16 + rl, chf);

  STAGE(0, 0);
  STAGE(1, 32);
  STAGE(2, 64);

#pragma unroll
  for (int t = 0; t < NST; ++t) {
    if (t + 3 < NST) STAGE((t + 3) & 3, (t + 3) * 32);
    const int rm = NST - 1 - t;
    if constexpr (PAN == 4) {
      if (rm >= 3) WAIT_VM(12);
      else if (rm == 2) WAIT_VM(8);
      else if (rm == 1) WAIT_VM(4);
      else WAIT_VM(0);
    } else {
      if (rm >= 3) WAIT_VM(6);
      else if (rm == 2) WAIT_VM(4);
      else if (rm == 1) WAIT_VM(2);
      else WAIT_VM(0);
    }
    __builtin_amdgcn_s_barrier();
    const short* lb = lds + (t & 3) * BUFS;
    short8 ah[2], al[2], bh[2], bl[2];
#pragma unroll
    for (int mi = 0; mi < 2; ++mi) {
      ah[mi] = *(const short8*)(lb + aoff[mi]);
      if constexpr (AH) al[mi] = *(const short8*)(lb + 2048 + aoff[mi]);
    }
#pragma unroll
    for (int ni = 0; ni < 2; ++ni) {
      bh[ni] = *(const short8*)(lb + ((AH && BH) ? 4096 : 2048) + boff[ni]);
      if constexpr (BH) bl[ni] = *(const short8*)(lb + 6144 + boff[ni]);
    }
#pragma unroll
    for (int mi = 0; mi < 2; ++mi)
#pragma unroll
      for (int ni = 0; ni < 2; ++ni) {
        acc[mi][ni] = __builtin_amdgcn_mfma_f32_16x16x32_bf16(ah[mi], bh[ni], acc[mi][ni], 0, 0, 0);
        if constexpr (BH)
          acc[mi][ni] = __builtin_amdgcn_mfma_f32_16x16x32_bf16(ah[mi], bl[ni], acc[mi][ni], 0, 0, 0);
        if constexpr (AH)
          acc[mi][ni] = __builtin_amdgcn_mfma_f32_16x16x32_bf16(al[mi], bh[ni], acc[mi][ni], 0, 0, 0);
      }
    __builtin_amdgcn_s_barrier();
  }

#pragma unroll
  for (int mi = 0; mi < 2; ++mi)
#pragma unroll
    for (int ni = 0; ni < 2; ++ni)
#pragma unroll
      for (int rr = 0; rr < 4; ++rr) {
        int row = m0 + wr + mi * 16 + (lane >> 4) * 4 + rr;
        int col = n0 + wc + ni * 16 + (lane & 15);
        long idx = (long)b * CC + (long)row * 512 + col;
        float v = acc[mi][ni][rr];
        if constexpr (EPI == 0) {
          __hip_bfloat16 h, l;
          hilo(v, h, l);
          ((__hip_bfloat16*)out1)[idx] = h;
          ((__hip_bfloat16*)out2)[idx] = l;
        } else if constexpr (EPI == 1) {
          ((float*)out1)[idx] = v;
        } else {
          ((__hip_bfloat16*)out1)[idx] = __float2bfloat16(v);
        }
      }
}

// ---------------------------------------------------------------------------
// Row softmax over 512 cols, fp32 in -> bf16 out. One row per WAVE,
// shuffle reductions, no LDS/barriers. Flat grid (1024), b = id&7.
// ---------------------------------------------------------------------------
__global__ __launch_bounds__(256) void softmax_k(const float* __restrict__ a,
                                                 __hip_bfloat16* __restrict__ o) {
  const int id = blockIdx.x;
  const int b = id & 7, rg = id >> 3;           // rg in [0,128)
  const int w = threadIdx.x >> 6, lane = threadIdx.x & 63;
  const long row = (long)b * 512 + rg * 4 + w;
  const float* rp = a + row * 512 + lane * 8;
  f32x4 v0 = *(const f32x4*)rp, v1 = *(const f32x4*)(rp + 4);
  float mx = fmaxf(fmaxf(fmaxf(v0[0], v0[1]), fmaxf(v0[2], v0[3])),
                   fmaxf(fmaxf(v1[0], v1[1]), fmaxf(v1[2], v1[3])));
#pragma unroll
  for (int s = 1; s < 64; s <<= 1) mx = fmaxf(mx, __shfl_xor(mx, s));
  float e[8];
#pragma unroll
  for (int k = 0; k < 4; ++k) {
    e[k] = expf(v0[k] - mx);
    e[4 + k] = expf(v1[k] - mx);
  }
  float sum = ((e[0] + e[1]) + (e[2] + e[3])) + ((e[4] + e[5]) + (e[6] + e[7]));
#pragma unroll
  for (int s = 1; s < 64; s <<= 1) sum += __shfl_xor(sum, s);
  const float inv = 1.0f / sum;
  short8 o8;
#pragma unroll
  for (int k = 0; k < 8; ++k) o8[k] = bfs(e[k] * inv);
  *(short8*)((short*)o + row * 512 + lane * 8) = o8;
}

// ---------------------------------------------------------------------------
// Big NT MFMA GEMM, 128x128 tile, M=512 N=4096 K=512. Flat grid (128,1,8),
// XCD-aware bijective swizzle. BK=32, 4 LDS buffers, depth-3 counted vmcnt.
// MODE 0: y = Mb (NT) Xt, permuted B-rows -> yvT bf16 (== permute+view).
// MODE 1: out = gamma*(w_mask (NT) yvT) + x, fp32 store, direct x read in
//   epilogue (round-5 proven; register x-prefetch REGRESSED: compiler spills
//   the 64-float tile at 96-VGPR target -> scratch traffic, +6 us. r6 lesson).
// ---------------------------------------------------------------------------
template <int MODE>
__global__ __launch_bounds__(256) void big_k(
    const __hip_bfloat16* __restrict__ Aw, const __hip_bfloat16* __restrict__ Bm,
    void* __restrict__ Cout, const float* __restrict__ x,
    const float* __restrict__ gammaPtr, long aStride) {
  const int b = blockIdx.z;
  const int lin = ((blockIdx.x & 7) << 4) | (blockIdx.x >> 3);  // XCD swizzle
  const int m0 = (lin & 3) * 128;
  const int n0 = (lin >> 2) * 128;
  const short* A = (const short*)(Aw + (long)b * aStride);
  const short* B = (const short*)(Bm + (long)b * CN);
  __shared__ short lds[4 * 8192];          // 64 KB: 4 x {A 128x32, B 128x32}
  const int tid = threadIdx.x, w = tid >> 6, lane = tid & 63;

  f32x4 acc[4][4] = {};
  const int wr = (w >> 1) * 64, wc = (w & 1) * 64;
  constexpr int NST = 16;

  auto STAGE = [&](int buf, int k0) {
    short* lb = lds + buf * 8192;
#pragma unroll
    for (int it = 0; it < 4; ++it) {
      int s = (w & 1) * 256 + it * 64 + lane;   // 0..511 within operand
      int r, ch;
      sdec32(s, r, ch);
      if (w < 2) {
        gload16(A + (long)(m0 + r) * 512 + k0 + ch * 8, lb + s * 8);
      } else {
        int gr = (MODE == 0) ? (n0 + (r & 15) * 8 + (r >> 4)) : (n0 + r);
        gload16(B + (long)gr * 512 + k0 + ch * 8, lb + 4096 + s * 8);
      }
    }
  };

  const int chf = lane >> 4, rl = lane & 15;
  int aoff[4], boff[4];
#pragma unroll
  for (int mi = 0; mi < 4; ++mi) aoff[mi] = cidx32(wr + mi * 16 + rl, chf);
#pragma unroll
  for (int ni = 0; ni < 4; ++ni) boff[ni] = 4096 + cidx32(wc + ni * 16 + rl, chf);

  STAGE(0, 0);
  STAGE(1, 32);
  STAGE(2, 64);

#pragma unroll
  for (int t = 0; t < NST; ++t) {
    if (t + 3 < NST) STAGE((t + 3) & 3, (t + 3) * 32);
    const int rm = NST - 1 - t;
    if (rm >= 3) WAIT_VM(12);
    else if (rm == 2) WAIT_VM(8);
    else if (rm == 1) WAIT_VM(4);
    else WAIT_VM(0);
    __builtin_amdgcn_s_barrier();
    const short* lb = lds + (t & 3) * 8192;
    short8 af[4], bfr[4];
#pragma unroll
    for (int mi = 0; mi < 4; ++mi) af[mi] = *(const short8*)(lb + aoff[mi]);
#pragma unroll
    for (int ni = 0; ni < 4; ++ni) bfr[ni] = *(const short8*)(lb + boff[ni]);
#pragma unroll
    for (int mi = 0; mi < 4; ++mi)
#pragma unroll
      for (int ni = 0; ni < 4; ++ni)
        acc[mi][ni] = __builtin_amdgcn_mfma_f32_16x16x32_bf16(af[mi], bfr[ni], acc[mi][ni], 0, 0, 0);
    __builtin_amdgcn_s_barrier();
  }

  if (MODE == 0) {
    __hip_bfloat16* yv = (__hip_bfloat16*)Cout + (long)b * CN;
    const int u = lane & 15;
#pragma unroll
    for (int mi = 0; mi < 4; ++mi)
#pragma unroll
      for (int ni = 0; ni < 4; ++ni) {
        int t = (wc >> 4) + ni;
        long base = ((long)(t * 512 + m0 + wr + mi * 16 + (lane >> 4) * 4)) * 512 +
                    (n0 >> 3) + u;
#pragma unroll
        for (int r = 0; r < 4; ++r)
          yv[base + (long)r * 512] = __float2bfloat16(acc[mi][ni][r]);
      }
  } else {
    float* outp = (float*)Cout + (long)b * CN;
    const float* xb = x + (long)b * CN;
    const float g0 = gammaPtr[0];
#pragma unroll
    for (int mi = 0; mi < 4; ++mi)
#pragma unroll
      for (int ni = 0; ni < 4; ++ni)
#pragma unroll
        for (int r = 0; r < 4; ++r) {
          long idx = (long)(m0 + wr + mi * 16 + (lane >> 4) * 4 + r) * HW +
                     n0 + wc + ni * 16 + (lane & 15);
          outp[idx] = g0 * acc[mi][ni][r] + xb[idx];
        }
  }
}

// ---------------------------------------------------------------------------
// Orchestration. Workspace ~107 MB.
// ---------------------------------------------------------------------------
extern "C" void kernel_launch(void* const* d_in, const int* in_sizes, int n_in,
                              void* d_out, int out_size, void* d_ws, size_t ws_size,
                              hipStream_t stream) {
  const float* x       = (const float*)d_in[0];
  const float* w_phi   = (const float*)d_in[1];
  const float* w_theta = (const float*)d_in[2];
  const float* w_g     = (const float*)d_in[3];
  const float* w_mask  = (const float*)d_in[4];
  const float* gamma   = (const float*)d_in[5];
  float* out = (float*)d_out;

  __hip_bfloat16* xhi = (__hip_bfloat16*)d_ws;
  __hip_bfloat16* xt  = xhi + BATCH * CN;
  __hip_bfloat16* gh  = xt + BATCH * CN;
  __hip_bfloat16* gl  = gh + BATCH * CC;
  __hip_bfloat16* t1h = gl + BATCH * CC;
  __hip_bfloat16* t1l = t1h + BATCH * CC;
  __hip_bfloat16* wph = t1l + BATCH * CC;
  __hip_bfloat16* wpl = wph + CC;
  __hip_bfloat16* wth = wpl + CC;
  __hip_bfloat16* wtl = wth + CC;
  __hip_bfloat16* wgT = wtl + CC;
  __hip_bfloat16* wm16 = wgT + CC;
  float* gpart = (float*)(wm16 + CC);     // 21 MB
  // aliases (stream-ordered lifetimes don't overlap):
  float* logits           = (float*)gh;
  __hip_bfloat16* attn16  = t1h;
  __hip_bfloat16* mb16    = t1l;
  __hip_bfloat16* yvT     = xhi;

  convx_k<<<dim3(64, 8, BATCH), 256, 0, stream>>>(x, xhi, xt);
  wprep_k<<<dim3(8, 8, 4), 256, 0, stream>>>(w_phi, w_theta, w_g, w_mask,
                                             wph, wpl, wth, wtl, wgT, wm16);
  gram_k<<<dim3(10, 4, BATCH), 256, 0, stream>>>(xhi, gpart);
  gred_k<<<dim3(160, 1, 1), 256, 0, stream>>>(gpart, gh, gl);
  nt_small<1, 1, 0><<<dim3(512, 1, 1), 256, 0, stream>>>(
      wph, wpl, gh, gl, 0, CC, t1h, t1l);
  nt_small<1, 1, 1><<<dim3(512, 1, 1), 256, 0, stream>>>(
      t1h, t1l, wth, wtl, CC, 0, logits, nullptr);
  softmax_k<<<dim3(1024, 1, 1), dim3(256), 0, stream>>>(logits, attn16);
  nt_small<0, 0, 2><<<dim3(512, 1, 1), 256, 0, stream>>>(
      attn16, nullptr, wgT, nullptr, CC, 0, mb16, nullptr);
  big_k<0><<<dim3(128, 1, BATCH), 256, 0, stream>>>(mb16, xt, yvT, nullptr, nullptr, CC);
  big_k<1><<<dim3(128, 1, BATCH), 256, 0, stream>>>(wm16, yvT, out, x, gamma, 0);
}

// Round 8
// 253.835 us; speedup vs baseline: 1.0339x; 1.0299x over previous
//
#include <hip/hip_runtime.h>
#include <hip/hip_bf16.h>

// (B,C,H,W) = (8,512,64,64)
constexpr int BATCH = 8;
constexpr int C = 512;
constexpr int HW = 4096;
constexpr long CN = (long)C * HW;   // 2,097,152
constexpr long CC = (long)C * C;    // 262,144

typedef __attribute__((ext_vector_type(8))) short short8;
typedef __attribute__((ext_vector_type(4))) short bf16x4;
typedef __attribute__((ext_vector_type(4))) float f32x4;

__device__ __forceinline__ void gload16(const void* g, void* l) {
  __builtin_amdgcn_global_load_lds(
      (const __attribute__((address_space(1))) void*)g,
      (__attribute__((address_space(3))) void*)l, 16, 0, 0);
}

__device__ __forceinline__ void hilo(float v, __hip_bfloat16& h, __hip_bfloat16& l) {
  h = __float2bfloat16(v);
  l = __float2bfloat16(v - __bfloat162float(h));
}
__device__ __forceinline__ short bfs(float v) {
  __hip_bfloat16 h = __float2bfloat16(v);
  return *(short*)&h;
}

// BK=32 LDS tile (rows x 32 k): 2 logical rows packed per 128B LDS row,
// XOR swizzle pos = ((r&1)*4 | ch) ^ ((r>>1)&7).
__device__ __forceinline__ int cidx32(int r, int ch) {   // short offset of 16B chunk
  return ((r >> 1) * 8 + ((((r & 1) << 2) | ch) ^ ((r >> 1) & 7))) * 8;
}
__device__ __forceinline__ void sdec32(int s, int& r, int& ch) {
  int R = s >> 3, q = s & 7, v = q ^ (R & 7);
  r = (R << 1) | (v >> 2);
  ch = v & 3;
}

#define WAIT_VM(n) asm volatile("s_waitcnt vmcnt(" #n ")" ::: "memory")

// ---------------------------------------------------------------------------
// convx: X fp32 [C,HW] -> Xhi bf16 [C,HW]; Xt bf16 [HW,C].
// ---------------------------------------------------------------------------
__global__ __launch_bounds__(256) void convx_k(
    const float* __restrict__ x, __hip_bfloat16* __restrict__ xhi,
    __hip_bfloat16* __restrict__ xt) {
  const int b = blockIdx.z;
  const int n0 = blockIdx.x * 64, c0 = blockIdx.y * 64;
  const float* xb = x + (long)b * CN;
  __shared__ short t[64 * 65];
  const int tid = threadIdx.x;
#pragma unroll
  for (int it = 0; it < 2; ++it) {
    int slot = it * 256 + tid;
    int r = slot >> 3, cc = (slot & 7) * 8;
    const float* src = xb + (long)(c0 + r) * HW + n0 + cc;
    f32x4 v0 = *(const f32x4*)src, v1 = *(const f32x4*)(src + 4);
    short8 hh;
#pragma unroll
    for (int e = 0; e < 4; ++e) {
      hh[e] = bfs(v0[e]);
      hh[4 + e] = bfs(v1[e]);
    }
    long idx = (long)b * CN + (long)(c0 + r) * HW + n0 + cc;
    *(short8*)((short*)xhi + idx) = hh;
#pragma unroll
    for (int e = 0; e < 8; ++e) t[r * 65 + cc + e] = hh[e];
  }
  __syncthreads();
#pragma unroll
  for (int it = 0; it < 2; ++it) {
    int slot = it * 256 + tid;
    int r = slot >> 3, cc = (slot & 7) * 8;
    short8 o;
#pragma unroll
    for (int e = 0; e < 8; ++e) o[e] = t[(cc + e) * 65 + r];
    *(short8*)((short*)xt + (long)b * CN + (long)(n0 + r) * C + c0 + cc) = o;
  }
}

// ---------------------------------------------------------------------------
// Weight prep: z=0 w_phi->hi/lo; z=1 w_theta->hi/lo; z=2 w_g->transpose bf16;
// z=3 w_mask->bf16.
// ---------------------------------------------------------------------------
__global__ __launch_bounds__(256) void wprep_k(
    const float* __restrict__ wphi, const float* __restrict__ wtheta,
    const float* __restrict__ wg, const float* __restrict__ wmask,
    __hip_bfloat16* __restrict__ wph, __hip_bfloat16* __restrict__ wpl,
    __hip_bfloat16* __restrict__ wth, __hip_bfloat16* __restrict__ wtl,
    __hip_bfloat16* __restrict__ wgT, __hip_bfloat16* __restrict__ wm16) {
  const int z = blockIdx.z;
  const int r0 = blockIdx.y * 64, c0 = blockIdx.x * 64;
  const int tid = threadIdx.x;
  if (z == 2) {
    __shared__ __hip_bfloat16 t[64][65];
#pragma unroll
    for (int i = 0; i < 16; ++i) {
      int e = i * 256 + tid;
      int r = e >> 6, c = e & 63;
      t[r][c] = __float2bfloat16(wg[(long)(r0 + r) * C + c0 + c]);
    }
    __syncthreads();
#pragma unroll
    for (int i = 0; i < 16; ++i) {
      int e = i * 256 + tid;
      int r = e >> 6, c = e & 63;
      wgT[(long)(c0 + r) * C + r0 + c] = t[c][r];
    }
  } else {
#pragma unroll
    for (int i = 0; i < 16; ++i) {
      int e = i * 256 + tid;
      int r = e >> 6, c = e & 63;
      long idx = (long)(r0 + r) * C + c0 + c;
      if (z == 0) {
        __hip_bfloat16 h, l;
        hilo(wphi[idx], h, l);
        wph[idx] = h; wpl[idx] = l;
      } else if (z == 1) {
        __hip_bfloat16 h, l;
        hilo(wtheta[idx], h, l);
        wth[idx] = h; wtl[idx] = l;
      } else {
        wm16[idx] = __float2bfloat16(wmask[idx]);
      }
    }
  }
}

// ---------------------------------------------------------------------------
// Gram partials: bf16, 128x128 triangular tiles (10/batch), K-split 4.
// BK=32, 4 LDS buffers, depth-3 counted vmcnt. XCD swizzle: b = f&7.
// ---------------------------------------------------------------------------
__global__ __launch_bounds__(256) void gram_k(
    const __hip_bfloat16* __restrict__ xhi, float* __restrict__ gpart) {
  const int f = blockIdx.x + 10 * (blockIdx.y + 4 * blockIdx.z);  // 0..319
  const int b = f & 7;
  const int rdec = f >> 3;            // 0..39
  const int ks = rdec / 10;           // 0..3
  const int tile = rdec % 10;
  int i = 0, rem0 = tile;
  while (rem0 >= 4 - i) { rem0 -= 4 - i; ++i; }
  const int j = i + rem0;
  const int m0 = i * 128, n0 = j * 128;

  const short* X = (const short*)(xhi + (long)b * CN);
  __shared__ short lds[4 * 8192];          // 64 KB: 4 x {A 128x32, B 128x32}
  const int tid = threadIdx.x, w = tid >> 6, lane = tid & 63;

  f32x4 acc[4][4] = {};
  const int wr = (w >> 1) * 64, wc = (w & 1) * 64;
  const int kbeg = ks * 1024;
  constexpr int NST = 32;

  auto STAGE = [&](int buf, int k0) {
#pragma unroll
    for (int it = 0; it < 4; ++it) {
      int s = (w & 1) * 256 + it * 64 + lane;   // 0..511 within operand
      int r, ch;
      sdec32(s, r, ch);
      int gr = (w < 2) ? (m0 + r) : (n0 + r);
      gload16(X + (long)gr * HW + k0 + ch * 8, lds + (buf * 8192 + (w >> 1) * 4096 + s * 8));
    }
  };

  const int chf = lane >> 4, rl = lane & 15;
  int aoff[4], boff[4];
#pragma unroll
  for (int mi = 0; mi < 4; ++mi) aoff[mi] = cidx32(wr + mi * 16 + rl, chf);
#pragma unroll
  for (int ni = 0; ni < 4; ++ni) boff[ni] = 4096 + cidx32(wc + ni * 16 + rl, chf);

  STAGE(0, kbeg);
  STAGE(1, kbeg + 32);
  STAGE(2, kbeg + 64);

#pragma unroll
  for (int t = 0; t < NST; ++t) {
    if (t + 3 < NST) STAGE((t + 3) & 3, kbeg + (t + 3) * 32);
    const int rm = NST - 1 - t;
    if (rm >= 3) WAIT_VM(12);
    else if (rm == 2) WAIT_VM(8);
    else if (rm == 1) WAIT_VM(4);
    else WAIT_VM(0);
    __builtin_amdgcn_s_barrier();
    const short* lb = lds + (t & 3) * 8192;
    short8 af[4], bfr[4];
#pragma unroll
    for (int mi = 0; mi < 4; ++mi) af[mi] = *(const short8*)(lb + aoff[mi]);
#pragma unroll
    for (int ni = 0; ni < 4; ++ni) bfr[ni] = *(const short8*)(lb + boff[ni]);
#pragma unroll
    for (int mi = 0; mi < 4; ++mi)
#pragma unroll
      for (int ni = 0; ni < 4; ++ni)
        acc[mi][ni] = __builtin_amdgcn_mfma_f32_16x16x32_bf16(af[mi], bfr[ni], acc[mi][ni], 0, 0, 0);
    __builtin_amdgcn_s_barrier();
  }

  float* P = gpart + ((((long)b * 10 + tile) * 4 + ks) << 14);
#pragma unroll
  for (int mi = 0; mi < 4; ++mi)
#pragma unroll
    for (int ni = 0; ni < 4; ++ni)
#pragma unroll
      for (int rr = 0; rr < 4; ++rr) {
        int row = wr + mi * 16 + (lane >> 4) * 4 + rr;
        int col = wc + ni * 16 + (lane & 15);
        P[row * 128 + col] = acc[mi][ni][rr];
      }
}

// ---------------------------------------------------------------------------
// Gram reduce: sum 4 K-partials over a 64x128 half-tile, hi/lo split, write
// direct + LDS-transposed mirror. Flat grid (160), b = id&7.
// ---------------------------------------------------------------------------
__global__ __launch_bounds__(256) void gred_k(
    const float* __restrict__ gpart, __hip_bfloat16* __restrict__ gh,
    __hip_bfloat16* __restrict__ gl) {
  const int id = blockIdx.x;
  const int b = id & 7;
  const int t2 = id >> 3;
  const int tile = t2 % 10;
  const int half = t2 / 10;
  int i = 0, rem = tile;
  while (rem >= 4 - i) { rem -= 4 - i; ++i; }
  const int j = i + rem;
  const int m0 = i * 128, n0 = j * 128;
  const float* P = gpart + (((long)b * 10 + tile) << 16) + half * 8192;
  __shared__ float T[128][65];
  const int tid = threadIdx.x;
  const long dbase = (long)b * CC;

#pragma unroll
  for (int q = 0; q < 8; ++q) {
    int e = q * 1024 + tid * 4;
    int r = e >> 7, c = e & 127;
    f32x4 s = {};
#pragma unroll
    for (int ks = 0; ks < 4; ++ks) s += *(const f32x4*)(P + (ks << 14) + e);
    bf16x4 hh, ll;
#pragma unroll
    for (int u = 0; u < 4; ++u) {
      __hip_bfloat16 h, l;
      hilo(s[u], h, l);
      hh[u] = *(short*)&h;
      ll[u] = *(short*)&l;
      T[c + u][r] = s[u];
    }
    long idx = dbase + (long)(m0 + half * 64 + r) * 512 + n0 + c;
    *(bf16x4*)((short*)gh + idx) = hh;
    *(bf16x4*)((short*)gl + idx) = ll;
  }
  if (i != j) {
    __syncthreads();
#pragma unroll
    for (int q = 0; q < 8; ++q) {
      int e = q * 1024 + tid * 4;
      int rp = e >> 6, cp = e & 63;
      bf16x4 hh, ll;
#pragma unroll
      for (int u = 0; u < 4; ++u) {
        __hip_bfloat16 h, l;
        hilo(T[rp][cp + u], h, l);
        hh[u] = *(short*)&h;
        ll[u] = *(short*)&l;
      }
      long idx = dbase + (long)(n0 + rp) * 512 + m0 + half * 64 + cp;
      *(bf16x4*)((short*)gh + idx) = hh;
      *(bf16x4*)((short*)gl + idx) = ll;
    }
  }
}

// ---------------------------------------------------------------------------
// Small NT MFMA GEMM: C[512,512] = A[512,K=512] * B[512,K]^T, per batch.
// AH/BH: hi/lo split operands (3 MFMA passes). EPI 0: hi/lo out; 1: fp32; 2: bf16.
// ROUND-5 STRUCTURE (BK=64, 2-buffer, drain-0): r7 proved BK32/depth-3
// REGRESSES here (+5.8 us) — barrier count doubles while compute/stage
// halves; at 64x64 tiles the per-stage fixed cost dominates.
// Flat grid (512), b = id&7 (XCD-aligned).
// ---------------------------------------------------------------------------
template <int AH, int BH, int EPI>
__global__ __launch_bounds__(256) void nt_small(
    const __hip_bfloat16* __restrict__ Ah_, const __hip_bfloat16* __restrict__ Al_,
    const __hip_bfloat16* __restrict__ Bh_, const __hip_bfloat16* __restrict__ Bl_,
    long aStr, long bStr, void* __restrict__ out1, void* __restrict__ out2) {
  const int id = blockIdx.x;
  const int b = id & 7;
  const int rest = id >> 3;
  const int m0 = (rest >> 3) * 64, n0 = (rest & 7) * 64;
  const short* Ahp = (const short*)(Ah_ + (long)b * aStr);
  const short* Alp = AH ? (const short*)(Al_ + (long)b * aStr) : nullptr;
  const short* Bhp = (const short*)(Bh_ + (long)b * bStr);
  const short* Blp = BH ? (const short*)(Bl_ + (long)b * bStr) : nullptr;
  constexpr int PAN = (AH && BH) ? 4 : 2;        // panels per buffer
  __shared__ short lds[2 * PAN * 4096];
  const int tid = threadIdx.x, w = tid >> 6, lane = tid & 63;

  f32x4 acc[2][2] = {};
  const int wr = (w >> 1) * 32, wc = (w & 1) * 32;

  auto STAGE = [&](int buf, int k0) {
    short* lb = lds + buf * PAN * 4096;
    if constexpr (AH && BH) {
      const short* src = (w == 0) ? Ahp : (w == 1) ? Alp : (w == 2) ? Bhp : Blp;
      const int rowbase = (w & 2) ? n0 : m0;
      short* lt = lb + w * 4096;
#pragma unroll
      for (int it = 0; it < 8; ++it) {
        int slot = it * 64 + lane;
        int r = slot >> 3, p = slot & 7, c = p ^ (r & 7);
        gload16(src + (long)(rowbase + r) * 512 + k0 + c * 8, lt + slot * 8);
      }
    } else {
      const short* src = (w < 2) ? Ahp : Bhp;
      const int rowbase = (w < 2) ? m0 : n0;
      short* lt = lb + (w >> 1) * 4096;
#pragma unroll
      for (int it = 0; it < 4; ++it) {
        int slot = (w & 1) * 256 + it * 64 + lane;
        int r = slot >> 3, p = slot & 7, c = p ^ (r & 7);
        gload16(src + (long)(rowbase + r) * 512 + k0 + c * 8, lt + slot * 8);
      }
    }
  };

  STAGE(0, 0);
  asm volatile("s_waitcnt vmcnt(0)" ::: "memory");
  __builtin_amdgcn_s_barrier();

  for (int t = 0; t < 8; ++t) {
    if (t < 7) STAGE((t + 1) & 1, (t + 1) * 64);
    const short* lb = lds + (t & 1) * PAN * 4096;
#pragma unroll
    for (int kh = 0; kh < 2; ++kh) {
      short8 ah[2], al[2], bh[2], bl[2];
      const int ch = kh * 4 + (lane >> 4);
#pragma unroll
      for (int mi = 0; mi < 2; ++mi) {
        int r = wr + mi * 16 + (lane & 15);
        int off = (r * 8 + (ch ^ (r & 7))) * 8;
        ah[mi] = *(const short8*)(lb + off);
        if constexpr (AH) al[mi] = *(const short8*)(lb + 4096 + off);
      }
#pragma unroll
      for (int ni = 0; ni < 2; ++ni) {
        int r = wc + ni * 16 + (lane & 15);
        int off = (r * 8 + (ch ^ (r & 7))) * 8;
        bh[ni] = *(const short8*)(lb + ((AH && BH) ? 8192 : 4096) + off);
        if constexpr (BH) bl[ni] = *(const short8*)(lb + 12288 + off);
      }
#pragma unroll
      for (int mi = 0; mi < 2; ++mi)
#pragma unroll
        for (int ni = 0; ni < 2; ++ni) {
          acc[mi][ni] = __builtin_amdgcn_mfma_f32_16x16x32_bf16(ah[mi], bh[ni], acc[mi][ni], 0, 0, 0);
          if constexpr (BH)
            acc[mi][ni] = __builtin_amdgcn_mfma_f32_16x16x32_bf16(ah[mi], bl[ni], acc[mi][ni], 0, 0, 0);
          if constexpr (AH)
            acc[mi][ni] = __builtin_amdgcn_mfma_f32_16x16x32_bf16(al[mi], bh[ni], acc[mi][ni], 0, 0, 0);
        }
    }
    asm volatile("s_waitcnt vmcnt(0)" ::: "memory");
    __builtin_amdgcn_s_barrier();
  }

#pragma unroll
  for (int mi = 0; mi < 2; ++mi)
#pragma unroll
    for (int ni = 0; ni < 2; ++ni)
#pragma unroll
      for (int rr = 0; rr < 4; ++rr) {
        int row = m0 + wr + mi * 16 + (lane >> 4) * 4 + rr;
        int col = n0 + wc + ni * 16 + (lane & 15);
        long idx = (long)b * CC + (long)row * 512 + col;
        float v = acc[mi][ni][rr];
        if constexpr (EPI == 0) {
          __hip_bfloat16 h, l;
          hilo(v, h, l);
          ((__hip_bfloat16*)out1)[idx] = h;
          ((__hip_bfloat16*)out2)[idx] = l;
        } else if constexpr (EPI == 1) {
          ((float*)out1)[idx] = v;
        } else {
          ((__hip_bfloat16*)out1)[idx] = __float2bfloat16(v);
        }
      }
}

// ---------------------------------------------------------------------------
// Row softmax over 512 cols, fp32 in -> bf16 out. One row per WAVE,
// shuffle reductions, no LDS/barriers. Flat grid (1024), b = id&7.
// ---------------------------------------------------------------------------
__global__ __launch_bounds__(256) void softmax_k(const float* __restrict__ a,
                                                 __hip_bfloat16* __restrict__ o) {
  const int id = blockIdx.x;
  const int b = id & 7, rg = id >> 3;           // rg in [0,128)
  const int w = threadIdx.x >> 6, lane = threadIdx.x & 63;
  const long row = (long)b * 512 + rg * 4 + w;
  const float* rp = a + row * 512 + lane * 8;
  f32x4 v0 = *(const f32x4*)rp, v1 = *(const f32x4*)(rp + 4);
  float mx = fmaxf(fmaxf(fmaxf(v0[0], v0[1]), fmaxf(v0[2], v0[3])),
                   fmaxf(fmaxf(v1[0], v1[1]), fmaxf(v1[2], v1[3])));
#pragma unroll
  for (int s = 1; s < 64; s <<= 1) mx = fmaxf(mx, __shfl_xor(mx, s));
  float e[8];
#pragma unroll
  for (int k = 0; k < 4; ++k) {
    e[k] = expf(v0[k] - mx);
    e[4 + k] = expf(v1[k] - mx);
  }
  float sum = ((e[0] + e[1]) + (e[2] + e[3])) + ((e[4] + e[5]) + (e[6] + e[7]));
#pragma unroll
  for (int s = 1; s < 64; s <<= 1) sum += __shfl_xor(sum, s);
  const float inv = 1.0f / sum;
  short8 o8;
#pragma unroll
  for (int k = 0; k < 8; ++k) o8[k] = bfs(e[k] * inv);
  *(short8*)((short*)o + row * 512 + lane * 8) = o8;
}

// ---------------------------------------------------------------------------
// Big NT MFMA GEMM, 128x128 tile, M=512 N=4096 K=512. Flat grid (128,1,8),
// XCD-aware bijective swizzle. BK=32, 4 LDS buffers, depth-3 counted vmcnt.
// MODE 0: y = Mb (NT) Xt, permuted B-rows -> yvT bf16 (== permute+view).
// MODE 1: out = gamma*(w_mask (NT) yvT) + xhi (bf16 residual read: halves the
//   x traffic, 64->32 MB; |bf16(x)-x| <= ~0.016 abs, within threshold).
// ---------------------------------------------------------------------------
template <int MODE>
__global__ __launch_bounds__(256) void big_k(
    const __hip_bfloat16* __restrict__ Aw, const __hip_bfloat16* __restrict__ Bm,
    void* __restrict__ Cout, const __hip_bfloat16* __restrict__ xh,
    const float* __restrict__ gammaPtr, long aStride) {
  const int b = blockIdx.z;
  const int lin = ((blockIdx.x & 7) << 4) | (blockIdx.x >> 3);  // XCD swizzle
  const int m0 = (lin & 3) * 128;
  const int n0 = (lin >> 2) * 128;
  const short* A = (const short*)(Aw + (long)b * aStride);
  const short* B = (const short*)(Bm + (long)b * CN);
  __shared__ short lds[4 * 8192];          // 64 KB: 4 x {A 128x32, B 128x32}
  const int tid = threadIdx.x, w = tid >> 6, lane = tid & 63;

  f32x4 acc[4][4] = {};
  const int wr = (w >> 1) * 64, wc = (w & 1) * 64;
  constexpr int NST = 16;

  auto STAGE = [&](int buf, int k0) {
    short* lb = lds + buf * 8192;
#pragma unroll
    for (int it = 0; it < 4; ++it) {
      int s = (w & 1) * 256 + it * 64 + lane;   // 0..511 within operand
      int r, ch;
      sdec32(s, r, ch);
      if (w < 2) {
        gload16(A + (long)(m0 + r) * 512 + k0 + ch * 8, lb + s * 8);
      } else {
        int gr = (MODE == 0) ? (n0 + (r & 15) * 8 + (r >> 4)) : (n0 + r);
        gload16(B + (long)gr * 512 + k0 + ch * 8, lb + 4096 + s * 8);
      }
    }
  };

  const int chf = lane >> 4, rl = lane & 15;
  int aoff[4], boff[4];
#pragma unroll
  for (int mi = 0; mi < 4; ++mi) aoff[mi] = cidx32(wr + mi * 16 + rl, chf);
#pragma unroll
  for (int ni = 0; ni < 4; ++ni) boff[ni] = 4096 + cidx32(wc + ni * 16 + rl, chf);

  STAGE(0, 0);
  STAGE(1, 32);
  STAGE(2, 64);

#pragma unroll
  for (int t = 0; t < NST; ++t) {
    if (t + 3 < NST) STAGE((t + 3) & 3, (t + 3) * 32);
    const int rm = NST - 1 - t;
    if (rm >= 3) WAIT_VM(12);
    else if (rm == 2) WAIT_VM(8);
    else if (rm == 1) WAIT_VM(4);
    else WAIT_VM(0);
    __builtin_amdgcn_s_barrier();
    const short* lb = lds + (t & 3) * 8192;
    short8 af[4], bfr[4];
#pragma unroll
    for (int mi = 0; mi < 4; ++mi) af[mi] = *(const short8*)(lb + aoff[mi]);
#pragma unroll
    for (int ni = 0; ni < 4; ++ni) bfr[ni] = *(const short8*)(lb + boff[ni]);
#pragma unroll
    for (int mi = 0; mi < 4; ++mi)
#pragma unroll
      for (int ni = 0; ni < 4; ++ni)
        acc[mi][ni] = __builtin_amdgcn_mfma_f32_16x16x32_bf16(af[mi], bfr[ni], acc[mi][ni], 0, 0, 0);
    __builtin_amdgcn_s_barrier();
  }

  if (MODE == 0) {
    __hip_bfloat16* yv = (__hip_bfloat16*)Cout + (long)b * CN;
    const int u = lane & 15;
#pragma unroll
    for (int mi = 0; mi < 4; ++mi)
#pragma unroll
      for (int ni = 0; ni < 4; ++ni) {
        int t = (wc >> 4) + ni;
        long base = ((long)(t * 512 + m0 + wr + mi * 16 + (lane >> 4) * 4)) * 512 +
                    (n0 >> 3) + u;
#pragma unroll
        for (int r = 0; r < 4; ++r)
          yv[base + (long)r * 512] = __float2bfloat16(acc[mi][ni][r]);
      }
  } else {
    float* outp = (float*)Cout + (long)b * CN;
    const __hip_bfloat16* xb = xh + (long)b * CN;
    const float g0 = gammaPtr[0];
#pragma unroll
    for (int mi = 0; mi < 4; ++mi)
#pragma unroll
      for (int ni = 0; ni < 4; ++ni)
#pragma unroll
        for (int r = 0; r < 4; ++r) {
          long idx = (long)(m0 + wr + mi * 16 + (lane >> 4) * 4 + r) * HW +
                     n0 + wc + ni * 16 + (lane & 15);
          outp[idx] = g0 * acc[mi][ni][r] + __bfloat162float(xb[idx]);
        }
  }
}

// ---------------------------------------------------------------------------
// Orchestration. Workspace ~115 MB. yvT lives in the (dead-after-gred) gpart
// region so xhi survives for big_k<1>'s bf16 residual read.
// ---------------------------------------------------------------------------
extern "C" void kernel_launch(void* const* d_in, const int* in_sizes, int n_in,
                              void* d_out, int out_size, void* d_ws, size_t ws_size,
                              hipStream_t stream) {
  const float* x       = (const float*)d_in[0];
  const float* w_phi   = (const float*)d_in[1];
  const float* w_theta = (const float*)d_in[2];
  const float* w_g     = (const float*)d_in[3];
  const float* w_mask  = (const float*)d_in[4];
  const float* gamma   = (const float*)d_in[5];
  float* out = (float*)d_out;

  __hip_bfloat16* xhi = (__hip_bfloat16*)d_ws;
  __hip_bfloat16* xt  = xhi + BATCH * CN;
  __hip_bfloat16* gh  = xt + BATCH * CN;
  __hip_bfloat16* gl  = gh + BATCH * CC;
  __hip_bfloat16* t1h = gl + BATCH * CC;
  __hip_bfloat16* t1l = t1h + BATCH * CC;
  __hip_bfloat16* wph = t1l + BATCH * CC;
  __hip_bfloat16* wpl = wph + CC;
  __hip_bfloat16* wth = wpl + CC;
  __hip_bfloat16* wtl = wth + CC;
  __hip_bfloat16* wgT = wtl + CC;
  __hip_bfloat16* wm16 = wgT + CC;
  float* gpart = (float*)(wm16 + CC);     // 21 MB live until gred_k
  // aliases (stream-ordered lifetimes don't overlap):
  float* logits           = (float*)gh;
  __hip_bfloat16* attn16  = t1h;
  __hip_bfloat16* mb16    = t1l;
  __hip_bfloat16* yvT     = (__hip_bfloat16*)gpart;   // 32 MB region (yvT > gpart)

  convx_k<<<dim3(64, 8, BATCH), 256, 0, stream>>>(x, xhi, xt);
  wprep_k<<<dim3(8, 8, 4), 256, 0, stream>>>(w_phi, w_theta, w_g, w_mask,
                                             wph, wpl, wth, wtl, wgT, wm16);
  gram_k<<<dim3(10, 4, BATCH), 256, 0, stream>>>(xhi, gpart);
  gred_k<<<dim3(160, 1, 1), 256, 0, stream>>>(gpart, gh, gl);
  nt_small<1, 1, 0><<<dim3(512, 1, 1), 256, 0, stream>>>(
      wph, wpl, gh, gl, 0, CC, t1h, t1l);
  nt_small<1, 1, 1><<<dim3(512, 1, 1), 256, 0, stream>>>(
      t1h, t1l, wth, wtl, CC, 0, logits, nullptr);
  softmax_k<<<dim3(1024, 1, 1), dim3(256), 0, stream>>>(logits, attn16);
  nt_small<0, 0, 2><<<dim3(512, 1, 1), 256, 0, stream>>>(
      attn16, nullptr, wgT, nullptr, CC, 0, mb16, nullptr);
  big_k<0><<<dim3(128, 1, BATCH), 256, 0, stream>>>(mb16, xt, yvT, nullptr, nullptr, CC);
  big_k<1><<<dim3(128, 1, BATCH), 256, 0, stream>>>(wm16, yvT, out, xhi, gamma, 0);
}